// Round 14
// baseline (159.300 us; speedup 1.0000x reference)
//
#include <hip/hip_runtime.h>
#include <stdint.h>

// RoPE attention, MI355X. S=4096, HID=1024, 16 heads x 64.
// R14: attention main loop has NO LDS, NO barriers. K/V are stored by k_gemm in
// FRAGMENT-LINEAR layouts (KF[h][kt][c][lane][16B], VF[h][kt][dt][kc][lane][16B],
// sigma order baked in), so each MFMA operand is one fully-coalesced 1KB
// global_load_dwordx4 from L2 (per-XCD working set 2MB). Math identical to R13
// (no-max exp2 softmax, sigma-PV, VALU denominator, kv-half split + LDS combine).
// ws layout: qbf 8MB | KF 8MB | VF 8MB | xbf 8MB | wbf 6MB | cos 512KB | sin 512KB

#define SEQLEN 4096
#define NHEAD 16
#define HDIM 64

typedef __bf16 bf16x8 __attribute__((ext_vector_type(8)));
typedef float f32x4 __attribute__((ext_vector_type(4)));
typedef float f32x16 __attribute__((ext_vector_type(16)));

__device__ __forceinline__ unsigned short f2bf(float f) {
  union { float f; unsigned int u; } v; v.f = f;
  unsigned int r = v.u + 0x7FFFu + ((v.u >> 16) & 1u);
  return (unsigned short)(r >> 16);
}
__device__ __forceinline__ unsigned int pkc(float lo, float hi) {
  union { __bf16 b[2]; unsigned int u; } z;
  z.b[0] = (__bf16)lo; z.b[1] = (__bf16)hi;
  return z.u;
}
__device__ __forceinline__ bf16x8 as_bf(uint4 v) { return __builtin_bit_cast(bf16x8, v); }
__device__ __forceinline__ f32x4 mfma16(bf16x8 a, bf16x8 b, f32x4 c) {
  return __builtin_amdgcn_mfma_f32_16x16x32_bf16(a, b, c, 0, 0, 0);
}
__device__ __forceinline__ f32x16 mfma32(bf16x8 a, bf16x8 b, f32x16 c) {
  return __builtin_amdgcn_mfma_f32_32x32x16_bf16(a, b, c, 0, 0, 0);
}

// ---------------- fp32 -> bf16 convert (x, then wq|wk|wv stacked) ----------------
__global__ __launch_bounds__(256) void k_convert(
    const float* __restrict__ x, const float* __restrict__ wq,
    const float* __restrict__ wk, const float* __restrict__ wv,
    unsigned short* __restrict__ xbf, unsigned short* __restrict__ wbf) {
  int i = blockIdx.x * 256 + threadIdx.x;   // one float4 per thread
  const int NX = SEQLEN * 1024 / 4;         // 1048576
  const int NW = 1024 * 1024 / 4;           // 262144 (pow2)
  float4 v;
  unsigned short* dst;
  int di;
  if (i < NX) {
    v = ((const float4*)x)[i]; dst = xbf; di = i;
  } else {
    int j = i - NX;
    const float4* src = (const float4*)((j < NW) ? wq : (j < 2 * NW) ? wk : wv);
    v = src[j & (NW - 1)];
    dst = wbf; di = j;
  }
  ushort4 o; o.x = f2bf(v.x); o.y = f2bf(v.y); o.z = f2bf(v.z); o.w = f2bf(v.w);
  ((ushort4*)dst)[di] = o;
}

// ---------------- RoPE cos/sin table (double precision) ----------------
__global__ __launch_bounds__(256) void k_table(float* __restrict__ ct, float* __restrict__ st) {
  int i = blockIdx.x * 256 + threadIdx.x;   // 4096*32 entries
  int s = i >> 5, j = i & 31;
  double inv = exp(-(double)j * 0.28782313662425572);  // ln(10000)/32
  double a = (double)s * inv;
  ct[i] = (float)cos(a);
  st[i] = (float)sin(a);
}

// ---------------- QKV GEMM (+RoPE epilogue, fragment-linear K/V stores) ----------------
__global__ __launch_bounds__(256) void k_gemm(
    const unsigned short* __restrict__ xbf, const unsigned short* __restrict__ wbf,
    const float* __restrict__ ct, const float* __restrict__ st,
    unsigned short* __restrict__ qbf, unsigned short* __restrict__ KF,
    unsigned short* __restrict__ VF) {
  __shared__ __align__(16) unsigned short As[2][128 * 40];
  __shared__ __align__(16) unsigned short Bs[2][128 * 40];
  const int t = threadIdx.x;
  const int bn = blockIdx.x, bm = blockIdx.y;
  const int lane = t & 63, wave = t >> 6;
  const int r = lane & 15, g = lane >> 4;
  const int wm = wave >> 1, wn = wave & 1;

  const int c0 = t, c1 = t + 256;
  const int ar0 = c0 >> 2, ao0 = (c0 & 3) * 16;
  const int ar1 = c1 >> 2, ao1 = (c1 & 3) * 16;

  const char* pA0 = (const char*)xbf + (size_t)(bm * 128 + ar0) * 2048 + ao0;
  const char* pA1 = (const char*)xbf + (size_t)(bm * 128 + ar1) * 2048 + ao1;
  const char* pB0 = (const char*)wbf + (size_t)(bn * 128 + ar0) * 2048 + ao0;
  const char* pB1 = (const char*)wbf + (size_t)(bn * 128 + ar1) * 2048 + ao1;

  uint4 ra0, ra1, rb0, rb1;
#define LD_TILE                                   \
  ra0 = *(const uint4*)pA0; ra1 = *(const uint4*)pA1; \
  rb0 = *(const uint4*)pB0; rb1 = *(const uint4*)pB1; \
  pA0 += 64; pA1 += 64; pB0 += 64; pB1 += 64;

  LD_TILE
  f32x4 zero4 = {0.f, 0.f, 0.f, 0.f};
  f32x4 acc[4][4];
#pragma unroll
  for (int m = 0; m < 4; ++m)
#pragma unroll
    for (int n = 0; n < 4; ++n) acc[m][n] = zero4;

  for (int kk = 0; kk < 32; ++kk) {
    unsigned short* Ac = As[kk & 1];
    unsigned short* Bc = Bs[kk & 1];
    *(uint4*)((char*)Ac + ar0 * 80 + ao0) = ra0;
    *(uint4*)((char*)Ac + ar1 * 80 + ao1) = ra1;
    *(uint4*)((char*)Bc + ar0 * 80 + ao0) = rb0;
    *(uint4*)((char*)Bc + ar1 * 80 + ao1) = rb1;
    __syncthreads();
    if (kk < 31) { LD_TILE }
    bf16x8 af[4], bfr[4];
#pragma unroll
    for (int m = 0; m < 4; ++m)
      af[m] = as_bf(*(const uint4*)((const char*)Ac + (wm * 64 + m * 16 + r) * 80 + g * 16));
#pragma unroll
    for (int n = 0; n < 4; ++n)
      bfr[n] = as_bf(*(const uint4*)((const char*)Bc + (wn * 64 + n * 16 + r) * 80 + g * 16));
#pragma unroll
    for (int m = 0; m < 4; ++m)
#pragma unroll
      for (int n = 0; n < 4; ++n)
        acc[m][n] = mfma16(af[m], bfr[n], acc[m][n]);
  }

  // Epilogue. C/D layout: col = lane&15 (=r), row = 4*g + reg.
  const int matid = bn >> 3;  // 0=q, 1=k, 2=v
#pragma unroll
  for (int m = 0; m < 4; ++m) {
    const int row0 = bm * 128 + wm * 64 + m * 16 + 4 * g;
#pragma unroll
    for (int n = 0; n < 4; ++n) {
      const int col = bn * 128 + wn * 64 + n * 16 + r;
      const int d = col & 63;
      const int hh = (col >> 6) & 15;
      if (matid < 2) {
        const int jdx = (col >> 1) & 31;
        const float sgn = (col & 1) ? 1.0f : -1.0f;
        const float qs = (matid == 0) ? 0.18033688011112042f : 1.0f;
#pragma unroll
        for (int j = 0; j < 4; ++j) {
          float v = acc[m][n][j];
          float p = __shfl_xor(v, 1);  // RoPE pair partner (col^1)
          int srow = row0 + j;
          float cv = ct[srow * 32 + jdx];
          float sv = st[srow * 32 + jdx];
          float o = (v * cv + p * sv * sgn) * qs;
          if (matid == 0) {
            qbf[(size_t)srow * 1024 + (hh * 64 + d)] = f2bf(o);
          } else {
            // KF[h][kt][c][lane=hi*32+li][8 bf16]: key li=srow&31, kt=srow>>5,
            // c=(d>>4)&3, hi=(d>>3)&1, elem d&7
            size_t kfi = (size_t)hh * 262144 + (size_t)(srow >> 5) * 2048 +
                         (size_t)((d >> 4) & 3) * 512 +
                         (size_t)((((d >> 3) & 1) * 32) + (srow & 31)) * 8 + (d & 7);
            KF[kfi] = f2bf(o);
          }
        }
      } else {
        // VF[h][kt][dt][kc][lane][16B]: b64 = keys row0..row0+3 at this d.
        ushort4 o;
        o.x = f2bf(acc[m][n][0]); o.y = f2bf(acc[m][n][1]);
        o.z = f2bf(acc[m][n][2]); o.w = f2bf(acc[m][n][3]);
        const int kt = row0 >> 5, q4 = (row0 >> 2) & 7;
        const int kc = q4 >> 2, bb = (q4 >> 1) & 1, h2 = q4 & 1;
        const int dt = d >> 5, l2 = d & 31;
        size_t off = (size_t)hh * 524288 + (size_t)kt * 4096 + (size_t)dt * 2048 +
                     (size_t)kc * 1024 + (size_t)(h2 * 32 + l2) * 16 + bb * 8;
        *(ushort4*)((char*)VF + off) = o;
      }
    }
  }
}

// ---------------- Flash attention (fragment-linear K/V, barrier-free loop) ----
// Block: 1 head x 128 q rows; waves 0-3 = q-tiles x keys 0..2047, waves 4-7 =
// keys 2048..4095. Per iter (32 keys): 4 coalesced 1KB K-frag loads + 4 V-frag
// loads from L2, 4 QK + 4 PV mfma32, exp2 softmax (no max), VALU denominator.
// LDS only for the end-of-kernel flash-combine of the two halves.
__global__ __launch_bounds__(512) void k_attn(
    const unsigned short* __restrict__ qbf, const unsigned short* __restrict__ KF,
    const unsigned short* __restrict__ VF, float* __restrict__ out) {
  __shared__ __align__(16) char smem[33280];
  const int t = threadIdx.x;
  // XCD swizzle: 512 blocks, 8 XCDs, 64 blocks/XCD -> 2 heads per XCD
  const int b = blockIdx.x;
  const int work = (b & 7) * 64 + (b >> 3);
  const int h = work >> 5;
  const int qb = work & 31;
  const int lane = t & 63, wave = t >> 6;
  const int qw = wave & 3, hf = wave >> 2;
  const int li = lane & 31, hi = lane >> 5;
  const int q0 = qb * 128 + qw * 32;

  // Q fragments (B-operand): lane holds q = q0+li, d = c*16 + hi*8 + j. Pre-scaled.
  bf16x8 qf[4];
#pragma unroll
  for (int c = 0; c < 4; ++c)
    qf[c] = as_bf(*(const uint4*)((const char*)qbf +
              (size_t)(q0 + li) * 2048 + h * 128 + c * 32 + hi * 16));

  f32x16 z16 = {0.f};
  f32x16 acc[2];            // O^T accum: d-tile dt, row=d, col=q
  acc[0] = z16; acc[1] = z16;
  float l4[4] = {0.f, 0.f, 0.f, 0.f};

  // fragment-linear pointers: one 16B chunk per lane, contiguous across the wave
  const char* pK = (const char*)KF + (size_t)h * 524288 + (size_t)hf * 262144 + lane * 16;
  const char* pV = (const char*)VF + (size_t)h * 524288 + (size_t)hf * 262144 + lane * 16;

  for (int j = 0; j < 64; ++j) {
    // ---- K fragments: 4 coalesced 1KB loads ----
    bf16x8 kf[4];
#pragma unroll
    for (int c = 0; c < 4; ++c)
      kf[c] = as_bf(*(const uint4*)(pK + c * 1024));
    // ---- V fragments: 4 coalesced 1KB loads (issued early; hide under QK/exp) ----
    bf16x8 vf2[2][2];
#pragma unroll
    for (int dt = 0; dt < 2; ++dt)
#pragma unroll
      for (int kc = 0; kc < 2; ++kc)
        vf2[dt][kc] = as_bf(*(const uint4*)(pV + dt * 2048 + kc * 1024));

    // ---- QK^T: S^T[key][q], one 32-key subtile ----
    f32x16 sT = z16;
    __builtin_amdgcn_s_setprio(1);
#pragma unroll
    for (int c = 0; c < 4; ++c)
      sT = mfma32(kf[c], qf[c], sT);
    __builtin_amdgcn_s_setprio(0);

    // ---- p = exp2(raw score); bounded, no max needed ----
#pragma unroll
    for (int i = 0; i < 16; ++i) sT[i] = __builtin_amdgcn_exp2f(sT[i]);

    // ---- denominator partials ----
#pragma unroll
    for (int i = 0; i < 4; ++i)
      l4[i] += (sT[i] + sT[i + 4]) + (sT[i + 8] + sT[i + 12]);

    // ---- pack P B-frags, then 4-MFMA PV cluster ----
    bf16x8 pfr[2];
#pragma unroll
    for (int kc = 0; kc < 2; ++kc) {
      const int bix = kc * 8;
      uint4 bw;
      bw.x = pkc(sT[bix + 0], sT[bix + 1]);
      bw.y = pkc(sT[bix + 2], sT[bix + 3]);
      bw.z = pkc(sT[bix + 4], sT[bix + 5]);
      bw.w = pkc(sT[bix + 6], sT[bix + 7]);
      pfr[kc] = as_bf(bw);
    }
    __builtin_amdgcn_s_setprio(1);
#pragma unroll
    for (int kc = 0; kc < 2; ++kc) {
      acc[0] = mfma32(vf2[0][kc], pfr[kc], acc[0]);
      acc[1] = mfma32(vf2[1][kc], pfr[kc], acc[1]);
    }
    __builtin_amdgcn_s_setprio(0);
    pK += 4096; pV += 4096;
  }

  float lrun = (l4[0] + l4[1]) + (l4[2] + l4[3]);
  // per-half full denominator (own hi-half + partner)
  float lhalf = lrun + __shfl_xor(lrun, 32);

  // ---- flash-combine of the two KV halves via LDS (plain add; no max) ----
  __syncthreads();
  float* shm = (float*)smem;
  if (hf == 1) {
    float* ab = shm + qw * 2048;   // [64 d][32 q]
#pragma unroll
    for (int dt = 0; dt < 2; ++dt)
#pragma unroll
      for (int i = 0; i < 16; ++i) {
        int d = (i & 3) + 8 * (i >> 2) + 4 * hi + 32 * dt;
        ab[d * 32 + li] = acc[dt][i];
      }
    if (hi == 0) shm[8192 + qw * 32 + li] = lhalf;
  }
  __syncthreads();
  if (hf == 0) {
    float* ab = shm + qw * 2048;
    float l1 = shm[8192 + qw * 32 + li];
    float linv = 1.0f / (lhalf + l1);
#pragma unroll
    for (int dt = 0; dt < 2; ++dt)
#pragma unroll
      for (int i = 0; i < 16; ++i) {
        int d = (i & 3) + 8 * (i >> 2) + 4 * hi + 32 * dt;
        acc[dt][i] = (acc[dt][i] + ab[d * 32 + li]) * linv;
      }
    __asm__ volatile("" ::: "memory");

    // ---- epilogue: transpose via LDS (wave-private region), coalesced stores ----
    float* eb = shm + qw * 2048;   // [32 q][33 d-pad] floats
#pragma unroll
    for (int dt = 0; dt < 2; ++dt) {
#pragma unroll
      for (int i = 0; i < 16; ++i)
        eb[li * 33 + ((i & 3) + 8 * (i >> 2) + 4 * hi)] = acc[dt][i];
      __asm__ volatile("" ::: "memory");
#pragma unroll
      for (int it = 0; it < 16; ++it) {
        int q = it * 2 + hi;
        float v = eb[q * 33 + li];
        out[(size_t)(q0 + q) * 1024 + h * 64 + dt * 32 + li] = v;
      }
      __asm__ volatile("" ::: "memory");
    }
  }
}

extern "C" void kernel_launch(void* const* d_in, const int* in_sizes, int n_in,
                              void* d_out, int out_size, void* d_ws, size_t ws_size,
                              hipStream_t stream) {
  const float* x  = (const float*)d_in[0];
  const float* wq = (const float*)d_in[1];
  const float* wk = (const float*)d_in[2];
  const float* wv = (const float*)d_in[3];
  float* out = (float*)d_out;
  char* ws = (char*)d_ws;

  unsigned short* qbf = (unsigned short*)(ws);
  unsigned short* KF  = (unsigned short*)(ws + ((size_t)8 << 20));
  unsigned short* VF  = (unsigned short*)(ws + ((size_t)16 << 20));
  unsigned short* xbf = (unsigned short*)(ws + ((size_t)24 << 20));
  unsigned short* wbf = (unsigned short*)(ws + ((size_t)32 << 20));
  float* ct = (float*)(ws + ((size_t)38 << 20));
  float* st = (float*)(ws + ((size_t)38 << 20) + ((size_t)512 << 10));

  k_convert<<<dim3(7168), dim3(256), 0, stream>>>(x, wq, wk, wv, xbf, wbf);
  k_table<<<dim3(512), dim3(256), 0, stream>>>(ct, st);
  k_gemm<<<dim3(24, 32), dim3(256), 0, stream>>>(xbf, wbf, ct, st, qbf, KF, VF);
  k_attn<<<dim3(512), dim3(512), 0, stream>>>(qbf, KF, VF, out);
}

// Round 15
// 155.009 us; speedup vs baseline: 1.0277x; 1.0277x over previous
//
#include <hip/hip_runtime.h>
#include <stdint.h>

// RoPE attention, MI355X. S=4096, HID=1024, 16 heads x 64.
// R15: R14 + register double-buffered prefetch in k_attn (iter j+1's 8 coalesced
// K/V fragment loads issued before iter j's compute -> L2 latency off the
// critical path), manual 2x unroll with named buffers (no runtime indexing).
// k_gemm: KF index hoisted to incremental form (fixes R14's epilogue slowdown).
// ws layout: qbf 8MB | KF 8MB | VF 8MB | xbf 8MB | wbf 6MB | cos 512KB | sin 512KB

#define SEQLEN 4096
#define NHEAD 16
#define HDIM 64

typedef __bf16 bf16x8 __attribute__((ext_vector_type(8)));
typedef float f32x4 __attribute__((ext_vector_type(4)));
typedef float f32x16 __attribute__((ext_vector_type(16)));

__device__ __forceinline__ unsigned short f2bf(float f) {
  union { float f; unsigned int u; } v; v.f = f;
  unsigned int r = v.u + 0x7FFFu + ((v.u >> 16) & 1u);
  return (unsigned short)(r >> 16);
}
__device__ __forceinline__ unsigned int pkc(float lo, float hi) {
  union { __bf16 b[2]; unsigned int u; } z;
  z.b[0] = (__bf16)lo; z.b[1] = (__bf16)hi;
  return z.u;
}
__device__ __forceinline__ bf16x8 as_bf(uint4 v) { return __builtin_bit_cast(bf16x8, v); }
__device__ __forceinline__ f32x4 mfma16(bf16x8 a, bf16x8 b, f32x4 c) {
  return __builtin_amdgcn_mfma_f32_16x16x32_bf16(a, b, c, 0, 0, 0);
}
__device__ __forceinline__ f32x16 mfma32(bf16x8 a, bf16x8 b, f32x16 c) {
  return __builtin_amdgcn_mfma_f32_32x32x16_bf16(a, b, c, 0, 0, 0);
}

// ---------------- fp32 -> bf16 convert (x, then wq|wk|wv stacked) ----------------
__global__ __launch_bounds__(256) void k_convert(
    const float* __restrict__ x, const float* __restrict__ wq,
    const float* __restrict__ wk, const float* __restrict__ wv,
    unsigned short* __restrict__ xbf, unsigned short* __restrict__ wbf) {
  int i = blockIdx.x * 256 + threadIdx.x;   // one float4 per thread
  const int NX = SEQLEN * 1024 / 4;         // 1048576
  const int NW = 1024 * 1024 / 4;           // 262144 (pow2)
  float4 v;
  unsigned short* dst;
  int di;
  if (i < NX) {
    v = ((const float4*)x)[i]; dst = xbf; di = i;
  } else {
    int j = i - NX;
    const float4* src = (const float4*)((j < NW) ? wq : (j < 2 * NW) ? wk : wv);
    v = src[j & (NW - 1)];
    dst = wbf; di = j;
  }
  ushort4 o; o.x = f2bf(v.x); o.y = f2bf(v.y); o.z = f2bf(v.z); o.w = f2bf(v.w);
  ((ushort4*)dst)[di] = o;
}

// ---------------- RoPE cos/sin table (double precision) ----------------
__global__ __launch_bounds__(256) void k_table(float* __restrict__ ct, float* __restrict__ st) {
  int i = blockIdx.x * 256 + threadIdx.x;   // 4096*32 entries
  int s = i >> 5, j = i & 31;
  double inv = exp(-(double)j * 0.28782313662425572);  // ln(10000)/32
  double a = (double)s * inv;
  ct[i] = (float)cos(a);
  st[i] = (float)sin(a);
}

// ---------------- QKV GEMM (+RoPE epilogue, fragment-linear K/V stores) ----------------
__global__ __launch_bounds__(256) void k_gemm(
    const unsigned short* __restrict__ xbf, const unsigned short* __restrict__ wbf,
    const float* __restrict__ ct, const float* __restrict__ st,
    unsigned short* __restrict__ qbf, unsigned short* __restrict__ KF,
    unsigned short* __restrict__ VF) {
  __shared__ __align__(16) unsigned short As[2][128 * 40];
  __shared__ __align__(16) unsigned short Bs[2][128 * 40];
  const int t = threadIdx.x;
  const int bn = blockIdx.x, bm = blockIdx.y;
  const int lane = t & 63, wave = t >> 6;
  const int r = lane & 15, g = lane >> 4;
  const int wm = wave >> 1, wn = wave & 1;

  const int c0 = t, c1 = t + 256;
  const int ar0 = c0 >> 2, ao0 = (c0 & 3) * 16;
  const int ar1 = c1 >> 2, ao1 = (c1 & 3) * 16;

  const char* pA0 = (const char*)xbf + (size_t)(bm * 128 + ar0) * 2048 + ao0;
  const char* pA1 = (const char*)xbf + (size_t)(bm * 128 + ar1) * 2048 + ao1;
  const char* pB0 = (const char*)wbf + (size_t)(bn * 128 + ar0) * 2048 + ao0;
  const char* pB1 = (const char*)wbf + (size_t)(bn * 128 + ar1) * 2048 + ao1;

  uint4 ra0, ra1, rb0, rb1;
#define LD_TILE                                   \
  ra0 = *(const uint4*)pA0; ra1 = *(const uint4*)pA1; \
  rb0 = *(const uint4*)pB0; rb1 = *(const uint4*)pB1; \
  pA0 += 64; pA1 += 64; pB0 += 64; pB1 += 64;

  LD_TILE
  f32x4 zero4 = {0.f, 0.f, 0.f, 0.f};
  f32x4 acc[4][4];
#pragma unroll
  for (int m = 0; m < 4; ++m)
#pragma unroll
    for (int n = 0; n < 4; ++n) acc[m][n] = zero4;

  for (int kk = 0; kk < 32; ++kk) {
    unsigned short* Ac = As[kk & 1];
    unsigned short* Bc = Bs[kk & 1];
    *(uint4*)((char*)Ac + ar0 * 80 + ao0) = ra0;
    *(uint4*)((char*)Ac + ar1 * 80 + ao1) = ra1;
    *(uint4*)((char*)Bc + ar0 * 80 + ao0) = rb0;
    *(uint4*)((char*)Bc + ar1 * 80 + ao1) = rb1;
    __syncthreads();
    if (kk < 31) { LD_TILE }
    bf16x8 af[4], bfr[4];
#pragma unroll
    for (int m = 0; m < 4; ++m)
      af[m] = as_bf(*(const uint4*)((const char*)Ac + (wm * 64 + m * 16 + r) * 80 + g * 16));
#pragma unroll
    for (int n = 0; n < 4; ++n)
      bfr[n] = as_bf(*(const uint4*)((const char*)Bc + (wn * 64 + n * 16 + r) * 80 + g * 16));
#pragma unroll
    for (int m = 0; m < 4; ++m)
#pragma unroll
      for (int n = 0; n < 4; ++n)
        acc[m][n] = mfma16(af[m], bfr[n], acc[m][n]);
  }

  // Epilogue. C/D layout: col = lane&15 (=r), row = 4*g + reg.
  const int matid = bn >> 3;  // 0=q, 1=k, 2=v
#pragma unroll
  for (int m = 0; m < 4; ++m) {
    const int row0 = bm * 128 + wm * 64 + m * 16 + 4 * g;
#pragma unroll
    for (int n = 0; n < 4; ++n) {
      const int col = bn * 128 + wn * 64 + n * 16 + r;
      const int d = col & 63;
      const int hh = (col >> 6) & 15;
      if (matid < 2) {
        const int jdx = (col >> 1) & 31;
        const float sgn = (col & 1) ? 1.0f : -1.0f;
        const float qs = (matid == 0) ? 0.18033688011112042f : 1.0f;
        // hoisted incremental KF index (srow>>5 and srow&31 stable +j, j<4, row0%4==0)
        size_t kfi0 = (size_t)hh * 262144 + (size_t)(row0 >> 5) * 2048 +
                      (size_t)((d >> 4) & 3) * 512 +
                      (size_t)((((d >> 3) & 1) * 32) + (row0 & 31)) * 8 + (d & 7);
#pragma unroll
        for (int j = 0; j < 4; ++j) {
          float v = acc[m][n][j];
          float p = __shfl_xor(v, 1);  // RoPE pair partner (col^1)
          int srow = row0 + j;
          float cv = ct[srow * 32 + jdx];
          float sv = st[srow * 32 + jdx];
          float o = (v * cv + p * sv * sgn) * qs;
          if (matid == 0) {
            qbf[(size_t)srow * 1024 + (hh * 64 + d)] = f2bf(o);
          } else {
            KF[kfi0 + (size_t)j * 8] = f2bf(o);
          }
        }
      } else {
        // VF[h][kt][dt][kc][lane][16B]: b64 = keys row0..row0+3 at this d.
        ushort4 o;
        o.x = f2bf(acc[m][n][0]); o.y = f2bf(acc[m][n][1]);
        o.z = f2bf(acc[m][n][2]); o.w = f2bf(acc[m][n][3]);
        const int kt = row0 >> 5, q4 = (row0 >> 2) & 7;
        const int kc = q4 >> 2, bb = (q4 >> 1) & 1, h2 = q4 & 1;
        const int dt = d >> 5, l2 = d & 31;
        size_t off = (size_t)hh * 524288 + (size_t)kt * 4096 + (size_t)dt * 2048 +
                     (size_t)kc * 1024 + (size_t)(h2 * 32 + l2) * 16 + bb * 8;
        *(ushort4*)((char*)VF + off) = o;
      }
    }
  }
}

// ---------------- Flash attention (fragment-linear K/V, barrier-free loop,
//                  register double-buffered prefetch) ----
__global__ __launch_bounds__(512) void k_attn(
    const unsigned short* __restrict__ qbf, const unsigned short* __restrict__ KF,
    const unsigned short* __restrict__ VF, float* __restrict__ out) {
  __shared__ __align__(16) char smem[33280];
  const int t = threadIdx.x;
  // XCD swizzle: 512 blocks, 8 XCDs, 64 blocks/XCD -> 2 heads per XCD
  const int b = blockIdx.x;
  const int work = (b & 7) * 64 + (b >> 3);
  const int h = work >> 5;
  const int qb = work & 31;
  const int lane = t & 63, wave = t >> 6;
  const int qw = wave & 3, hf = wave >> 2;
  const int li = lane & 31, hi = lane >> 5;
  const int q0 = qb * 128 + qw * 32;

  // Q fragments (B-operand): lane holds q = q0+li, d = c*16 + hi*8 + j. Pre-scaled.
  bf16x8 qf[4];
#pragma unroll
  for (int c = 0; c < 4; ++c)
    qf[c] = as_bf(*(const uint4*)((const char*)qbf +
              (size_t)(q0 + li) * 2048 + h * 128 + c * 32 + hi * 16));

  f32x16 z16 = {0.f};
  f32x16 acc[2];            // O^T accum: d-tile dt, row=d, col=q
  acc[0] = z16; acc[1] = z16;
  float l4[4] = {0.f, 0.f, 0.f, 0.f};

  // fragment-linear pointers: one 16B chunk per lane, contiguous across the wave
  const char* pK = (const char*)KF + (size_t)h * 524288 + (size_t)hf * 262144 + lane * 16;
  const char* pV = (const char*)VF + (size_t)h * 524288 + (size_t)hf * 262144 + lane * 16;

#define LDFRAG(kb, vb)                               \
  kb##0 = *(const uint4*)(pK);                       \
  kb##1 = *(const uint4*)(pK + 1024);                \
  kb##2 = *(const uint4*)(pK + 2048);                \
  kb##3 = *(const uint4*)(pK + 3072);                \
  vb##0 = *(const uint4*)(pV);                       \
  vb##1 = *(const uint4*)(pV + 1024);                \
  vb##2 = *(const uint4*)(pV + 2048);                \
  vb##3 = *(const uint4*)(pV + 3072);                \
  pK += 4096; pV += 4096;

  // compute one 32-key tile from fragment registers
#define BODY(kb, vb)                                                           \
  {                                                                            \
    f32x16 sT = z16;                                                           \
    __builtin_amdgcn_s_setprio(1);                                             \
    sT = mfma32(as_bf(kb##0), qf[0], sT);                                      \
    sT = mfma32(as_bf(kb##1), qf[1], sT);                                      \
    sT = mfma32(as_bf(kb##2), qf[2], sT);                                      \
    sT = mfma32(as_bf(kb##3), qf[3], sT);                                      \
    __builtin_amdgcn_s_setprio(0);                                             \
    _Pragma("unroll")                                                          \
    for (int i = 0; i < 16; ++i) sT[i] = __builtin_amdgcn_exp2f(sT[i]);        \
    _Pragma("unroll")                                                          \
    for (int i = 0; i < 4; ++i)                                                \
      l4[i] += (sT[i] + sT[i + 4]) + (sT[i + 8] + sT[i + 12]);                 \
    uint4 bw0, bw1;                                                            \
    bw0.x = pkc(sT[0], sT[1]);  bw0.y = pkc(sT[2], sT[3]);                     \
    bw0.z = pkc(sT[4], sT[5]);  bw0.w = pkc(sT[6], sT[7]);                     \
    bw1.x = pkc(sT[8], sT[9]);  bw1.y = pkc(sT[10], sT[11]);                   \
    bw1.z = pkc(sT[12], sT[13]); bw1.w = pkc(sT[14], sT[15]);                  \
    bf16x8 p0 = as_bf(bw0), p1 = as_bf(bw1);                                   \
    __builtin_amdgcn_s_setprio(1);                                             \
    acc[0] = mfma32(as_bf(vb##0), p0, acc[0]);                                 \
    acc[1] = mfma32(as_bf(vb##2), p0, acc[1]);                                 \
    acc[0] = mfma32(as_bf(vb##1), p1, acc[0]);                                 \
    acc[1] = mfma32(as_bf(vb##3), p1, acc[1]);                                 \
    __builtin_amdgcn_s_setprio(0);                                             \
  }

  uint4 ka0, ka1, ka2, ka3, va0, va1, va2, va3;   // buffer A
  uint4 kb0, kb1, kb2, kb3, vb0, vb1, vb2, vb3;   // buffer B

  LDFRAG(ka, va)
  for (int j = 0; j < 64; j += 2) {
    LDFRAG(kb, vb)          // prefetch j+1 (always valid: j+1 <= 63)
    BODY(ka, va)            // compute j
    if (j + 2 < 64) { LDFRAG(ka, va) }   // prefetch j+2
    BODY(kb, vb)            // compute j+1
  }

  float lrun = (l4[0] + l4[1]) + (l4[2] + l4[3]);
  // per-half full denominator (own hi-half + partner)
  float lhalf = lrun + __shfl_xor(lrun, 32);

  // ---- flash-combine of the two KV halves via LDS (plain add; no max) ----
  __syncthreads();
  float* shm = (float*)smem;
  if (hf == 1) {
    float* ab = shm + qw * 2048;   // [64 d][32 q]
#pragma unroll
    for (int dt = 0; dt < 2; ++dt)
#pragma unroll
      for (int i = 0; i < 16; ++i) {
        int d = (i & 3) + 8 * (i >> 2) + 4 * hi + 32 * dt;
        ab[d * 32 + li] = acc[dt][i];
      }
    if (hi == 0) shm[8192 + qw * 32 + li] = lhalf;
  }
  __syncthreads();
  if (hf == 0) {
    float* ab = shm + qw * 2048;
    float l1 = shm[8192 + qw * 32 + li];
    float linv = 1.0f / (lhalf + l1);
#pragma unroll
    for (int dt = 0; dt < 2; ++dt)
#pragma unroll
      for (int i = 0; i < 16; ++i) {
        int d = (i & 3) + 8 * (i >> 2) + 4 * hi + 32 * dt;
        acc[dt][i] = (acc[dt][i] + ab[d * 32 + li]) * linv;
      }
    __asm__ volatile("" ::: "memory");

    // ---- epilogue: transpose via LDS (wave-private region), coalesced stores ----
    float* eb = shm + qw * 2048;   // [32 q][33 d-pad] floats
#pragma unroll
    for (int dt = 0; dt < 2; ++dt) {
#pragma unroll
      for (int i = 0; i < 16; ++i)
        eb[li * 33 + ((i & 3) + 8 * (i >> 2) + 4 * hi)] = acc[dt][i];
      __asm__ volatile("" ::: "memory");
#pragma unroll
      for (int it = 0; it < 16; ++it) {
        int q = it * 2 + hi;
        float v = eb[q * 33 + li];
        out[(size_t)(q0 + q) * 1024 + h * 64 + dt * 32 + li] = v;
      }
      __asm__ volatile("" ::: "memory");
    }
  }
}

extern "C" void kernel_launch(void* const* d_in, const int* in_sizes, int n_in,
                              void* d_out, int out_size, void* d_ws, size_t ws_size,
                              hipStream_t stream) {
  const float* x  = (const float*)d_in[0];
  const float* wq = (const float*)d_in[1];
  const float* wk = (const float*)d_in[2];
  const float* wv = (const float*)d_in[3];
  float* out = (float*)d_out;
  char* ws = (char*)d_ws;

  unsigned short* qbf = (unsigned short*)(ws);
  unsigned short* KF  = (unsigned short*)(ws + ((size_t)8 << 20));
  unsigned short* VF  = (unsigned short*)(ws + ((size_t)16 << 20));
  unsigned short* xbf = (unsigned short*)(ws + ((size_t)24 << 20));
  unsigned short* wbf = (unsigned short*)(ws + ((size_t)32 << 20));
  float* ct = (float*)(ws + ((size_t)38 << 20));
  float* st = (float*)(ws + ((size_t)38 << 20) + ((size_t)512 << 10));

  k_convert<<<dim3(7168), dim3(256), 0, stream>>>(x, wq, wk, wv, xbf, wbf);
  k_table<<<dim3(512), dim3(256), 0, stream>>>(ct, st);
  k_gemm<<<dim3(24, 32), dim3(256), 0, stream>>>(xbf, wbf, ct, st, qbf, KF, VF);
  k_attn<<<dim3(512), dim3(512), 0, stream>>>(qbf, KF, VF, out);
}